// Round 8
// baseline (2164.765 us; speedup 1.0000x reference)
//
#include <hip/hip_runtime.h>
#include <hip/hip_bf16.h>
#include <stdint.h>

#define N_PTS 16384
#define S_OUT 1024

// Inputs: float32. Outputs: float32.
// d_out = new_xyz f32[4*1024*3] ++ new_points f32[4*1024*128].
// d_ws  = knn indices int32[4*1024*32].
//
// sq-formula fingerprints vs harness np ref (output-1 absmax):
//   (sumq - 2*dot) + sumx, dot in {asc,desc} x {mul/add,FMA}: 0.19921875 (all)
//   true distance (f32-direct == f64-direct): 0.3359375
//   knn: classic PointNet square_distance association —
//   sq = (sumq + sumx) - 2*dot, dot = ascending FMA (np.matmul/BLAS k=3
//   micro-kernel: acc=rn(a0*b0); acc=fma(a1,b1,acc); acc=fma(a2,b2,acc)).

typedef float v2f __attribute__((ext_vector_type(2)));

// ---------------------------------------------------------------------------
// Kernel 1: farthest point sampling (bit-exact vs np ref).
// REVERTED VERBATIM to the measured-best R15 structure (fps 1638us, round-4
// bench). Tail-variant ledger: R14 1718 / R15 1638 / R16 2134 / R17 2306 /
// R18 1757 — R15 is the empirical optimum; later "improvements" all
// lengthened the post-barrier dependent chain or spilled registers.
// Distance math bit-exact: packed f32 pairs, mul/add ascending (contract
// off), fminf; value-only reduce; winner threads scan + LDS atomicMin;
// tie semantics = np.argmax (lowest index on ties) via descending scan +
// atomicMin over per-thread lowest matching indices.
// ---------------------------------------------------------------------------
__global__ __launch_bounds__(512)
__attribute__((amdgpu_waves_per_eu(2, 2)))
void fps_kernel(
    const float* __restrict__ xyz,
    float* __restrict__ out_newxyz)
{
#pragma clang fp contract(off)
  const int b    = blockIdx.x;
  const int tid  = threadIdx.x;
  const int lane = tid & 63;
  const int wid  = tid >> 6;           // 8 waves
  const float* base = xyz + (size_t)b * N_PTS * 3;

  v2f px[16], py[16], pz[16], dist[16];
#pragma unroll
  for (int i = 0; i < 16; ++i) {
    int n0 = (tid * 32 + 2 * i) * 3;
    px[i] = (v2f){ base[n0 + 0], base[n0 + 3] };
    py[i] = (v2f){ base[n0 + 1], base[n0 + 4] };
    pz[i] = (v2f){ base[n0 + 2], base[n0 + 5] };
    dist[i] = (v2f){ 1e10f, 1e10f };
  }

  __shared__ float swave[2][8];
  __shared__ unsigned s_idx[2];

  if (tid == 0) { s_idx[0] = 0xFFFFFFFFu; s_idx[1] = 0xFFFFFFFFu; }

  float cx = base[0], cy = base[1], cz = base[2];

  for (int s = 0; s < S_OUT; ++s) {
    if (tid == 0) {
      size_t o = ((size_t)b * S_OUT + s) * 3;
      out_newxyz[o + 0] = cx;
      out_newxyz[o + 1] = cy;
      out_newxyz[o + 2] = cz;
    }
    if (s == S_OUT - 1) break;

    const v2f cx2 = (v2f){ cx, cx };
    const v2f cy2 = (v2f){ cy, cy };
    const v2f cz2 = (v2f){ cz, cz };

    // ---- distance update (packed pairs) + value-only max chains ----
    float m0 = -1.0f, m1 = -1.0f, m2 = -1.0f, m3 = -1.0f;
#pragma unroll
    for (int i = 0; i < 16; ++i) {
      v2f dx = px[i] - cx2;
      v2f dy = py[i] - cy2;
      v2f dz = pz[i] - cz2;
      v2f dd = (dx * dx + dy * dy) + dz * dz;   // contract OFF: mul/add exact
      v2f dm = __builtin_elementwise_min(dist[i], dd);
      dist[i] = dm;
      // fmaxf(fmaxf(a,b),c) folds to v_max3_f32; 4 independent chains
      if ((i & 3) == 0)      m0 = fmaxf(fmaxf(m0, dm.x), dm.y);
      else if ((i & 3) == 1) m1 = fmaxf(fmaxf(m1, dm.x), dm.y);
      else if ((i & 3) == 2) m2 = fmaxf(fmaxf(m2, dm.x), dm.y);
      else                   m3 = fmaxf(fmaxf(m3, dm.x), dm.y);
    }
    const float lm = fmaxf(fmaxf(m0, m1), fmaxf(m2, m3));

    // ---- wave reduce (value only, f32 butterfly) ----
    float wm = lm;
#pragma unroll
    for (int off = 1; off < 64; off <<= 1)
      wm = fmaxf(wm, __shfl_xor(wm, off));

    const int p = s & 1;           // double buffer: 1 barrier gap is safe
    if (lane == 0) swave[p][wid] = wm;
    __syncthreads();

    // ---- block max: all threads merge the 8 wave maxima (max3 tree) ----
    float M = swave[p][0];
    {
      float a = fmaxf(fmaxf(swave[p][1], swave[p][2]), swave[p][3]);
      float c = fmaxf(fmaxf(swave[p][4], swave[p][5]), swave[p][6]);
      M = fmaxf(fmaxf(M, swave[p][7]), fmaxf(a, c));
    }

    // ---- index find: only local-max==M threads scan (usually 1) ----
    if (lm == M) {
      int bi = 0;
#pragma unroll
      for (int j = 31; j >= 0; --j) {         // descending: keep lowest j
        float d = dist[j >> 1][j & 1];
        bi = (d == M) ? j : bi;
      }
      atomicMin(&s_idx[p], (unsigned)(tid * 32 + bi));
    }
    if (tid == 0) s_idx[p ^ 1] = 0xFFFFFFFFu;  // reset other buffer
    __syncthreads();

    unsigned n = s_idx[p];
    n = __builtin_amdgcn_readfirstlane(n);
    const float* pc = base + (size_t)n * 3;
    cx = pc[0]; cy = pc[1]; cz = pc[2];
  }
}

// ---------------------------------------------------------------------------
// Kernel 2: exact 32-NN per centroid, two-level radix select.
// ROUND 19: LDS key cache. Previously all 16384 keys were COMPUTED THREE
// times (pass1/2/3): 3x ~770 VALU insts/thread + 3x 192KB xyz re-read from
// L2 per block (x4096 blocks ~ 2.4GB L2 traffic). Now pass1 computes keys
// once and stores skey[16384] (64KB LDS, j*256+tid access = banks 0-31,
// 2 lanes/bank = conflict-free); passes 2/3 are LDS reads + ~3 ALU.
// LDS total ~79KB -> still 2 blocks/CU (158 <= 160KB), occupancy unchanged.
// Key bits, (key,idx) tie handling, and emitted SET identical; output order
// within the below-threshold prefix is arbitrary as before (consumed by an
// order-invariant max in mlp).
//   sq = (sumq + sumx) - 2*dot,  dot = ascending FMA (BLAS sgemm k=3).
// ---------------------------------------------------------------------------
__global__ __launch_bounds__(256, 2) void knn_kernel(
    const float* __restrict__ xyz,
    const float* __restrict__ newxyz,
    int* __restrict__ knn_out)
{
  const int bs  = blockIdx.x;        // b*1024 + s
  const int b   = bs >> 10;
  const int tid = threadIdx.x;
  const float* base = xyz + (size_t)b * N_PTS * 3;

  const float qx = newxyz[(size_t)bs * 3 + 0];
  const float qy = newxyz[(size_t)bs * 3 + 1];
  const float qz = newxyz[(size_t)bs * 3 + 2];
  const float sumq = __fadd_rn(__fadd_rn(__fmul_rn(qx, qx), __fmul_rn(qy, qy)),
                               __fmul_rn(qz, qz));

  __shared__ unsigned skey[16384];   // 64KB key cache
  __shared__ unsigned hist[2048];
  __shared__ unsigned tsum[256];
  __shared__ unsigned long long cand[512];
  __shared__ unsigned long long s_min;
  __shared__ int s_b1, s_r1, s_b2, s_r2, s_cntL, s_cntC;

  for (int i = tid; i < 2048; i += 256) hist[i] = 0;
  if (tid == 0) { s_cntL = 0; s_cntC = 0; }
  __syncthreads();

  // pass 1: compute keys ONCE, cache in LDS, level-1 histogram (bits 31:21)
  for (int j = 0; j < 64; ++j) {
    int n = j * 256 + tid;
    float x = base[n * 3 + 0];
    float y = base[n * 3 + 1];
    float z = base[n * 3 + 2];
    float sumx = __fadd_rn(__fadd_rn(__fmul_rn(x, x), __fmul_rn(y, y)),
                           __fmul_rn(z, z));
    float dot  = __fmul_rn(qx, x);
    dot = fmaf(qy, y, dot);
    dot = fmaf(qz, z, dot);
    float sq   = __fsub_rn(__fadd_rn(sumq, sumx), __fmul_rn(2.0f, dot));
    unsigned u = __float_as_uint(sq);
    u ^= (u & 0x80000000u) ? 0xFFFFFFFFu : 0x80000000u;
    skey[n] = u;
    atomicAdd(&hist[u >> 21], 1u);
  }
  __syncthreads();

  unsigned ts = 0;
#pragma unroll
  for (int u = 0; u < 8; ++u) ts += hist[tid * 8 + u];
  tsum[tid] = ts;
  __syncthreads();

  if (tid == 0) {       // find level-1 bin containing rank 32
    unsigned acc = 0; int t2 = 0;
    for (; t2 < 256; ++t2) { unsigned h = tsum[t2]; if (acc + h >= 32u) break; acc += h; }
    int u2 = t2 * 8;
    for (;; ++u2) { unsigned h = hist[u2]; if (acc + h >= 32u) break; acc += h; }
    s_b1 = u2; s_r1 = 32 - (int)acc;      // rank within bin b1, >= 1
  }
  __syncthreads();
  const unsigned b1 = (unsigned)s_b1;
  const int r1 = s_r1;

  // clear histogram for level 2
  for (int i = tid; i < 2048; i += 256) hist[i] = 0;
  __syncthreads();

  // pass 2: level-2 histogram (bits 20:10) of cached keys inside bin b1
  for (int j = 0; j < 64; ++j) {
    unsigned u = skey[j * 256 + tid];
    if ((u >> 21) == b1) atomicAdd(&hist[(u >> 10) & 0x7FFu], 1u);
  }
  __syncthreads();

  ts = 0;
#pragma unroll
  for (int u = 0; u < 8; ++u) ts += hist[tid * 8 + u];
  tsum[tid] = ts;
  __syncthreads();

  if (tid == 0) {       // find level-2 sub-bin containing rank r1
    unsigned acc = 0; int t2 = 0;
    for (; t2 < 256; ++t2) { unsigned h = tsum[t2]; if (acc + h >= (unsigned)r1) break; acc += h; }
    int u2 = t2 * 8;
    for (;; ++u2) { unsigned h = hist[u2]; if (acc + h >= (unsigned)r1) break; acc += h; }
    s_b2 = u2; s_r2 = r1 - (int)acc;      // rank within sub-bin b2, >= 1
  }
  __syncthreads();
  const unsigned b2 = (unsigned)s_b2;

  int* outp = knn_out + (size_t)bs * 32;

  // pass 3: emit below-(b1,b2) directly; exact 22-bit-prefix matches -> cand
  for (int j = 0; j < 64; ++j) {
    int n = j * 256 + tid;
    unsigned u = skey[n];
    unsigned bin = u >> 21;
    if (bin < b1) {
      int p = atomicAdd(&s_cntL, 1);
      outp[p] = n;
    } else if (bin == b1) {
      unsigned sub = (u >> 10) & 0x7FFu;
      if (sub < b2) {
        int p = atomicAdd(&s_cntL, 1);
        outp[p] = n;
      } else if (sub == b2) {
        int p = atomicAdd(&s_cntC, 1);
        if (p < 512) cand[p] = ((unsigned long long)u << 32) | (unsigned)n;
      }
    }
  }
  __syncthreads();

  const int r   = s_r2;
  const int cl  = s_cntL;             // == 32 - r
  const int cnt = min(s_cntC, 512);
  unsigned long long last = 0ull;
  for (int i = 0; i < r; ++i) {
    if (tid == 0) s_min = ~0ull;
    __syncthreads();
    for (int p = tid; p < cnt; p += 256) {
      unsigned long long v = cand[p];
      if (i == 0 ? 1 : (v > last)) atomicMin(&s_min, v);
    }
    __syncthreads();
    unsigned long long m = s_min;
    if (tid == 0) outp[cl + i] = (int)(unsigned)(m & 0xFFFFFFFFull);
    last = m;
    __syncthreads();
  }
}

// ---------------------------------------------------------------------------
// Kernel 3: fused gather + (dense+BN+ReLU)x3 + max over K. 2 centroids per
// block (256 threads = 2 groups x 128). All f32; weights staged per-layer in
// LDS. Gathered indices clamped to [0,16383] defensively. (UNCHANGED)
// ---------------------------------------------------------------------------
__global__ __launch_bounds__(256, 2) void mlp_kernel(
    const float* __restrict__ xyz,
    const float* __restrict__ points,
    const float* __restrict__ newxyz,
    const int* __restrict__ knn,
    const float* __restrict__ w0, const float* __restrict__ g0,
    const float* __restrict__ b0, const float* __restrict__ mm0,
    const float* __restrict__ mv0,
    const float* __restrict__ w1, const float* __restrict__ g1,
    const float* __restrict__ b1_, const float* __restrict__ mm1,
    const float* __restrict__ mv1,
    const float* __restrict__ w2, const float* __restrict__ g2,
    const float* __restrict__ b2_, const float* __restrict__ mm2,
    const float* __restrict__ mv2,
    float* __restrict__ out1)
{
  const int tid = threadIdx.x;
  const int BS0 = blockIdx.x * 2;

  __shared__ __align__(16) float xT[2][67][36];  // input feats (c-major); reused as a2
  __shared__ __align__(16) float a1[2][64][36];  // layer-1 out; reused as k-max partials
  __shared__ __align__(16) float wbuf[8192];     // current layer weights (f32)

  // ---- gather: x = [grouped_xyz - new_xyz (3) ; grouped_points (64)] ----
  {
    const int sg = tid >> 7;
    const int j  = (tid >> 2) & 31;
    const int cq = tid & 3;
    const int S  = BS0 + sg;
    const int bb = S >> 10;
    const int n  = knn[(size_t)S * 32 + j] & (N_PTS - 1);   // defensive clamp
    const float* pbase = points + ((size_t)bb * N_PTS + n) * 64;
    const float* xbase = xyz + ((size_t)bb * N_PTS + n) * 3;
    for (int c = cq; c < 67; c += 4) {
      float v;
      if (c < 3) v = __fsub_rn(xbase[c], newxyz[(size_t)S * 3 + c]);
      else       v = pbase[c - 3];
      xT[sg][c][j] = v;
    }
  }
  for (int i = tid; i < 67 * 64; i += 256) wbuf[i] = w0[i];
  __syncthreads();

  const int sg = tid >> 7;
  const int t  = tid & 127;

  // ---- layer 1: 67 -> 64 ----
  {
    const int ot = t & 15, kt = t >> 4;
    const int o0 = ot * 4, k0 = kt * 4;
    float acc[4][4] = {};
    for (int c = 0; c < 67; ++c) {
      float4 xv = *(const float4*)&xT[sg][c][k0];
      float4 wq = *(const float4*)&wbuf[c * 64 + o0];
      float wv[4] = { wq.x, wq.y, wq.z, wq.w };
      float xs[4] = { xv.x, xv.y, xv.z, xv.w };
#pragma unroll
      for (int a = 0; a < 4; ++a)
#pragma unroll
        for (int k2 = 0; k2 < 4; ++k2)
          acc[a][k2] = fmaf(wv[a], xs[k2], acc[a][k2]);
    }
#pragma unroll
    for (int jj = 0; jj < 4; ++jj) {
      int o = o0 + jj;
      float A  = rsqrtf(mv0[o] + 1e-3f) * g0[o];
      float Bc = b0[o] - mm0[o] * A;
      float4 y;
      y.x = fmaxf(fmaf(acc[jj][0], A, Bc), 0.0f);
      y.y = fmaxf(fmaf(acc[jj][1], A, Bc), 0.0f);
      y.z = fmaxf(fmaf(acc[jj][2], A, Bc), 0.0f);
      y.w = fmaxf(fmaf(acc[jj][3], A, Bc), 0.0f);
      *(float4*)&a1[sg][o][k0] = y;
    }
  }
  __syncthreads();
  for (int i = tid; i < 64 * 64; i += 256) wbuf[i] = w1[i];
  __syncthreads();

  // ---- layer 2: 64 -> 64 (reads a1, writes a2 = xT region) ----
  {
    const int ot = t & 15, kt = t >> 4;
    const int o0 = ot * 4, k0 = kt * 4;
    float acc[4][4] = {};
    for (int c = 0; c < 64; ++c) {
      float4 xv = *(const float4*)&a1[sg][c][k0];
      float4 wq = *(const float4*)&wbuf[c * 64 + o0];
      float wv[4] = { wq.x, wq.y, wq.z, wq.w };
      float xs[4] = { xv.x, xv.y, xv.z, xv.w };
#pragma unroll
      for (int a = 0; a < 4; ++a)
#pragma unroll
        for (int k2 = 0; k2 < 4; ++k2)
          acc[a][k2] = fmaf(wv[a], xs[k2], acc[a][k2]);
    }
#pragma unroll
    for (int jj = 0; jj < 4; ++jj) {
      int o = o0 + jj;
      float A  = rsqrtf(mv1[o] + 1e-3f) * g1[o];
      float Bc = b1_[o] - mm1[o] * A;
      float4 y;
      y.x = fmaxf(fmaf(acc[jj][0], A, Bc), 0.0f);
      y.y = fmaxf(fmaf(acc[jj][1], A, Bc), 0.0f);
      y.z = fmaxf(fmaf(acc[jj][2], A, Bc), 0.0f);
      y.w = fmaxf(fmaf(acc[jj][3], A, Bc), 0.0f);
      *(float4*)&xT[sg][o][k0] = y;
    }
  }
  __syncthreads();
  for (int i = tid; i < 64 * 128; i += 256) wbuf[i] = w2[i];
  __syncthreads();

  // ---- layer 3: 64 -> 128, BN+ReLU folded into max over k ----
  float* pm = &a1[0][0][0];          // [2][128][4] partial maxima
  {
    const int ot = t & 31, kt = t >> 5;
    const int o0 = ot * 4, k0 = kt * 8;
    float acc[4][8] = {};
    for (int c = 0; c < 64; ++c) {
      float4 xa = *(const float4*)&xT[sg][c][k0];
      float4 xb = *(const float4*)&xT[sg][c][k0 + 4];
      float4 wq = *(const float4*)&wbuf[c * 128 + o0];
      float wv[4] = { wq.x, wq.y, wq.z, wq.w };
      float xs[8] = { xa.x, xa.y, xa.z, xa.w, xb.x, xb.y, xb.z, xb.w };
#pragma unroll
      for (int a = 0; a < 4; ++a)
#pragma unroll
        for (int k2 = 0; k2 < 8; ++k2)
          acc[a][k2] = fmaf(wv[a], xs[k2], acc[a][k2]);
    }
#pragma unroll
    for (int jj = 0; jj < 4; ++jj) {
      int o = o0 + jj;
      float A  = rsqrtf(mv2[o] + 1e-3f) * g2[o];
      float Bc = b2_[o] - mm2[o] * A;
      float m = 0.0f;                 // relu>=0: max(0, max_k bn) == max_k relu(bn)
#pragma unroll
      for (int kk = 0; kk < 8; ++kk)
        m = fmaxf(m, fmaf(acc[jj][kk], A, Bc));
      pm[((sg * 128 + o) << 2) + kt] = m;
    }
  }
  __syncthreads();
  {
    const int sg2 = tid >> 7, o = tid & 127;
    const int basep = (sg2 * 128 + o) << 2;
    float m = fmaxf(fmaxf(pm[basep + 0], pm[basep + 1]),
                    fmaxf(pm[basep + 2], pm[basep + 3]));
    out1[(size_t)(BS0 + sg2) * 128 + o] = m;
  }
}

extern "C" void kernel_launch(void* const* d_in, const int* in_sizes, int n_in,
                              void* d_out, int out_size, void* d_ws, size_t ws_size,
                              hipStream_t stream) {
  const float* xyz    = (const float*)d_in[0];
  const float* points = (const float*)d_in[1];
  const float* w0  = (const float*)d_in[2];
  const float* g0  = (const float*)d_in[3];
  const float* b0  = (const float*)d_in[4];
  const float* mm0 = (const float*)d_in[5];
  const float* mv0 = (const float*)d_in[6];
  const float* w1  = (const float*)d_in[7];
  const float* g1  = (const float*)d_in[8];
  const float* b1  = (const float*)d_in[9];
  const float* mm1 = (const float*)d_in[10];
  const float* mv1 = (const float*)d_in[11];
  const float* w2  = (const float*)d_in[12];
  const float* g2  = (const float*)d_in[13];
  const float* b2  = (const float*)d_in[14];
  const float* mm2 = (const float*)d_in[15];
  const float* mv2 = (const float*)d_in[16];

  float* out      = (float*)d_out;                       // new_xyz f32[12288]
  float* out_pts  = out + (size_t)4 * 1024 * 3;          // new_points f32[524288]
  int*   knn      = (int*)d_ws;                          // 4*1024*32 int32

  fps_kernel<<<4, 512, 0, stream>>>(xyz, out);
  knn_kernel<<<4096, 256, 0, stream>>>(xyz, out, knn);
  mlp_kernel<<<2048, 256, 0, stream>>>(xyz, points, out, knn,
      w0, g0, b0, mm0, mv0, w1, g1, b1, mm1, mv1, w2, g2, b2, mm2, mv2,
      out_pts);
}

// Round 9
// 1957.658 us; speedup vs baseline: 1.1058x; 1.1058x over previous
//
#include <hip/hip_runtime.h>
#include <hip/hip_bf16.h>
#include <stdint.h>

#define N_PTS 16384
#define S_OUT 1024

// Inputs: float32. Outputs: float32.
// d_out = new_xyz f32[4*1024*3] ++ new_points f32[4*1024*128].
// d_ws  = knn indices int32[4*1024*32].
//
// sq-formula fingerprints vs harness np ref (output-1 absmax):
//   (sumq - 2*dot) + sumx, dot in {asc,desc} x {mul/add,FMA}: 0.19921875 (all)
//   true distance (f32-direct == f64-direct): 0.3359375
//   knn: classic PointNet square_distance association —
//   sq = (sumq + sumx) - 2*dot, dot = ascending FMA (np.matmul/BLAS k=3
//   micro-kernel: acc=rn(a0*b0); acc=fma(a1,b1,acc); acc=fma(a2,b2,acc)).

typedef float v2f __attribute__((ext_vector_type(2)));

// ---------------------------------------------------------------------------
// Kernel 1: farthest point sampling (bit-exact vs np ref).
// VERBATIM R15 structure (measured-best; re-verified round 8 at 1642us).
// Tail-variant ledger: R14 1718 / R15 1638 / R16 2134 / R17 2306 / R18 1757.
// DO NOT restructure further — 3 attempts to beat R15 all regressed.
// ---------------------------------------------------------------------------
__global__ __launch_bounds__(512)
__attribute__((amdgpu_waves_per_eu(2, 2)))
void fps_kernel(
    const float* __restrict__ xyz,
    float* __restrict__ out_newxyz)
{
#pragma clang fp contract(off)
  const int b    = blockIdx.x;
  const int tid  = threadIdx.x;
  const int lane = tid & 63;
  const int wid  = tid >> 6;           // 8 waves
  const float* base = xyz + (size_t)b * N_PTS * 3;

  v2f px[16], py[16], pz[16], dist[16];
#pragma unroll
  for (int i = 0; i < 16; ++i) {
    int n0 = (tid * 32 + 2 * i) * 3;
    px[i] = (v2f){ base[n0 + 0], base[n0 + 3] };
    py[i] = (v2f){ base[n0 + 1], base[n0 + 4] };
    pz[i] = (v2f){ base[n0 + 2], base[n0 + 5] };
    dist[i] = (v2f){ 1e10f, 1e10f };
  }

  __shared__ float swave[2][8];
  __shared__ unsigned s_idx[2];

  if (tid == 0) { s_idx[0] = 0xFFFFFFFFu; s_idx[1] = 0xFFFFFFFFu; }

  float cx = base[0], cy = base[1], cz = base[2];

  for (int s = 0; s < S_OUT; ++s) {
    if (tid == 0) {
      size_t o = ((size_t)b * S_OUT + s) * 3;
      out_newxyz[o + 0] = cx;
      out_newxyz[o + 1] = cy;
      out_newxyz[o + 2] = cz;
    }
    if (s == S_OUT - 1) break;

    const v2f cx2 = (v2f){ cx, cx };
    const v2f cy2 = (v2f){ cy, cy };
    const v2f cz2 = (v2f){ cz, cz };

    // ---- distance update (packed pairs) + value-only max chains ----
    float m0 = -1.0f, m1 = -1.0f, m2 = -1.0f, m3 = -1.0f;
#pragma unroll
    for (int i = 0; i < 16; ++i) {
      v2f dx = px[i] - cx2;
      v2f dy = py[i] - cy2;
      v2f dz = pz[i] - cz2;
      v2f dd = (dx * dx + dy * dy) + dz * dz;   // contract OFF: mul/add exact
      v2f dm = __builtin_elementwise_min(dist[i], dd);
      dist[i] = dm;
      // fmaxf(fmaxf(a,b),c) folds to v_max3_f32; 4 independent chains
      if ((i & 3) == 0)      m0 = fmaxf(fmaxf(m0, dm.x), dm.y);
      else if ((i & 3) == 1) m1 = fmaxf(fmaxf(m1, dm.x), dm.y);
      else if ((i & 3) == 2) m2 = fmaxf(fmaxf(m2, dm.x), dm.y);
      else                   m3 = fmaxf(fmaxf(m3, dm.x), dm.y);
    }
    const float lm = fmaxf(fmaxf(m0, m1), fmaxf(m2, m3));

    // ---- wave reduce (value only, f32 butterfly) ----
    float wm = lm;
#pragma unroll
    for (int off = 1; off < 64; off <<= 1)
      wm = fmaxf(wm, __shfl_xor(wm, off));

    const int p = s & 1;           // double buffer: 1 barrier gap is safe
    if (lane == 0) swave[p][wid] = wm;
    __syncthreads();

    // ---- block max: all threads merge the 8 wave maxima (max3 tree) ----
    float M = swave[p][0];
    {
      float a = fmaxf(fmaxf(swave[p][1], swave[p][2]), swave[p][3]);
      float c = fmaxf(fmaxf(swave[p][4], swave[p][5]), swave[p][6]);
      M = fmaxf(fmaxf(M, swave[p][7]), fmaxf(a, c));
    }

    // ---- index find: only local-max==M threads scan (usually 1) ----
    if (lm == M) {
      int bi = 0;
#pragma unroll
      for (int j = 31; j >= 0; --j) {         // descending: keep lowest j
        float d = dist[j >> 1][j & 1];
        bi = (d == M) ? j : bi;
      }
      atomicMin(&s_idx[p], (unsigned)(tid * 32 + bi));
    }
    if (tid == 0) s_idx[p ^ 1] = 0xFFFFFFFFu;  // reset other buffer
    __syncthreads();

    unsigned n = s_idx[p];
    n = __builtin_amdgcn_readfirstlane(n);
    const float* pc = base + (size_t)n * 3;
    cx = pc[0]; cy = pc[1]; cz = pc[2];
  }
}

// ---------------------------------------------------------------------------
// Kernel 2: exact 32-NN per centroid, two-level radix select.
// ROUND 20: pass fusion, occupancy-preserving. R19's 64KB key cache cut
// occupancy 8->2 blocks/CU and REGRESSED (+200us) — lesson: occupancy >
// recompute avoidance here. This version keeps LDS small (~21KB -> 7
// blocks/CU) and removes pass 3's full sweep in the typical case:
//  - pass 2 (fused): compute key once; bin<b1 -> emit directly (<=31/blk);
//    bin==b1 -> sub-histogram AND stash (key,n) into bbuf[1024] (8KB).
//  - pass 3: if bin-b1 population <= 1024 (typical), scan ONLY the stash
//    (<=1024 LDS reads block-wide vs 16384 key recomputes + 192KB L2).
//    Overflow -> fallback full rescan (original pass-3 semantics).
// Emitted SET, tie handling ((key,idx) order), and the sorted rank-r
// extraction are identical; order within the below-threshold prefix was
// already nondeterministic (atomicAdd) and is consumed order-invariantly.
//   sq = (sumq + sumx) - 2*dot,  dot = ascending FMA (BLAS sgemm k=3).
// ---------------------------------------------------------------------------
#define BBUF_CAP 1024

__global__ __launch_bounds__(256, 2) void knn_kernel(
    const float* __restrict__ xyz,
    const float* __restrict__ newxyz,
    int* __restrict__ knn_out)
{
  const int bs  = blockIdx.x;        // b*1024 + s
  const int b   = bs >> 10;
  const int tid = threadIdx.x;
  const float* base = xyz + (size_t)b * N_PTS * 3;

  const float qx = newxyz[(size_t)bs * 3 + 0];
  const float qy = newxyz[(size_t)bs * 3 + 1];
  const float qz = newxyz[(size_t)bs * 3 + 2];
  const float sumq = __fadd_rn(__fadd_rn(__fmul_rn(qx, qx), __fmul_rn(qy, qy)),
                               __fmul_rn(qz, qz));

  __shared__ unsigned hist[2048];
  __shared__ unsigned tsum[256];
  __shared__ unsigned long long cand[512];
  __shared__ unsigned long long bbuf[BBUF_CAP];
  __shared__ unsigned long long s_min;
  __shared__ int s_b1, s_r1, s_b2, s_r2, s_cntL, s_cntC, s_cntB;

  for (int i = tid; i < 2048; i += 256) hist[i] = 0;
  if (tid == 0) { s_cntL = 0; s_cntC = 0; s_cntB = 0; }
  __syncthreads();

#define KNN_KEY(n, u)                                                          \
    float x = base[(n) * 3 + 0];                                               \
    float y = base[(n) * 3 + 1];                                               \
    float z = base[(n) * 3 + 2];                                               \
    float sumx = __fadd_rn(__fadd_rn(__fmul_rn(x, x), __fmul_rn(y, y)),        \
                           __fmul_rn(z, z));                                   \
    float dot  = __fmul_rn(qx, x);                                             \
    dot = fmaf(qy, y, dot);                                                    \
    dot = fmaf(qz, z, dot);                                                    \
    float sq   = __fsub_rn(__fadd_rn(sumq, sumx), __fmul_rn(2.0f, dot));       \
    unsigned u = __float_as_uint(sq);                                          \
    u ^= (u & 0x80000000u) ? 0xFFFFFFFFu : 0x80000000u;

  // pass 1: level-1 histogram (bits 31:21)
  for (int j = 0; j < 64; ++j) {
    int n = j * 256 + tid;
    KNN_KEY(n, u)
    atomicAdd(&hist[u >> 21], 1u);
  }
  __syncthreads();

  unsigned ts = 0;
#pragma unroll
  for (int u = 0; u < 8; ++u) ts += hist[tid * 8 + u];
  tsum[tid] = ts;
  __syncthreads();

  if (tid == 0) {       // find level-1 bin containing rank 32
    unsigned acc = 0; int t2 = 0;
    for (; t2 < 256; ++t2) { unsigned h = tsum[t2]; if (acc + h >= 32u) break; acc += h; }
    int u2 = t2 * 8;
    for (;; ++u2) { unsigned h = hist[u2]; if (acc + h >= 32u) break; acc += h; }
    s_b1 = u2; s_r1 = 32 - (int)acc;      // rank within bin b1, >= 1
  }
  __syncthreads();
  const unsigned b1 = (unsigned)s_b1;
  const int r1 = s_r1;

  // clear histogram for level 2
  for (int i = tid; i < 2048; i += 256) hist[i] = 0;
  __syncthreads();

  int* outp = knn_out + (size_t)bs * 32;

  // pass 2 (fused): emit bin<b1 directly; bin==b1 -> sub-hist + stash
  for (int j = 0; j < 64; ++j) {
    int n = j * 256 + tid;
    KNN_KEY(n, u)
    unsigned bin = u >> 21;
    if (bin < b1) {
      int p = atomicAdd(&s_cntL, 1);
      outp[p] = n;
    } else if (bin == b1) {
      atomicAdd(&hist[(u >> 10) & 0x7FFu], 1u);
      int q = atomicAdd(&s_cntB, 1);
      if (q < BBUF_CAP)
        bbuf[q] = ((unsigned long long)u << 32) | (unsigned)n;
    }
  }
  __syncthreads();

  ts = 0;
#pragma unroll
  for (int u = 0; u < 8; ++u) ts += hist[tid * 8 + u];
  tsum[tid] = ts;
  __syncthreads();

  if (tid == 0) {       // find level-2 sub-bin containing rank r1
    unsigned acc = 0; int t2 = 0;
    for (; t2 < 256; ++t2) { unsigned h = tsum[t2]; if (acc + h >= (unsigned)r1) break; acc += h; }
    int u2 = t2 * 8;
    for (;; ++u2) { unsigned h = hist[u2]; if (acc + h >= (unsigned)r1) break; acc += h; }
    s_b2 = u2; s_r2 = r1 - (int)acc;      // rank within sub-bin b2, >= 1
  }
  __syncthreads();
  const unsigned b2 = (unsigned)s_b2;
  const int cntB = s_cntB;

  // pass 3: typical = scan stash only; overflow -> full rescan of bin b1
  if (cntB <= BBUF_CAP) {
    for (int q = tid; q < cntB; q += 256) {
      unsigned long long v = bbuf[q];
      unsigned u = (unsigned)(v >> 32);
      unsigned sub = (u >> 10) & 0x7FFu;
      if (sub < b2) {
        int p = atomicAdd(&s_cntL, 1);
        outp[p] = (int)(unsigned)(v & 0xFFFFFFFFull);
      } else if (sub == b2) {
        int p = atomicAdd(&s_cntC, 1);
        if (p < 512) cand[p] = v;
      }
    }
  } else {
    for (int j = 0; j < 64; ++j) {
      int n = j * 256 + tid;
      KNN_KEY(n, u)
      if ((u >> 21) == b1) {
        unsigned sub = (u >> 10) & 0x7FFu;
        if (sub < b2) {
          int p = atomicAdd(&s_cntL, 1);
          outp[p] = n;
        } else if (sub == b2) {
          int p = atomicAdd(&s_cntC, 1);
          if (p < 512) cand[p] = ((unsigned long long)u << 32) | (unsigned)n;
        }
      }
    }
  }
  __syncthreads();
#undef KNN_KEY

  const int r   = s_r2;
  const int cl  = s_cntL;             // == 32 - r
  const int cnt = min(s_cntC, 512);
  unsigned long long last = 0ull;
  for (int i = 0; i < r; ++i) {
    if (tid == 0) s_min = ~0ull;
    __syncthreads();
    for (int p = tid; p < cnt; p += 256) {
      unsigned long long v = cand[p];
      if (i == 0 ? 1 : (v > last)) atomicMin(&s_min, v);
    }
    __syncthreads();
    unsigned long long m = s_min;
    if (tid == 0) outp[cl + i] = (int)(unsigned)(m & 0xFFFFFFFFull);
    last = m;
    __syncthreads();
  }
}

// ---------------------------------------------------------------------------
// Kernel 3: fused gather + (dense+BN+ReLU)x3 + max over K. 2 centroids per
// block (256 threads = 2 groups x 128). All f32; weights staged per-layer in
// LDS. Gathered indices clamped to [0,16383] defensively. (UNCHANGED)
// ---------------------------------------------------------------------------
__global__ __launch_bounds__(256, 2) void mlp_kernel(
    const float* __restrict__ xyz,
    const float* __restrict__ points,
    const float* __restrict__ newxyz,
    const int* __restrict__ knn,
    const float* __restrict__ w0, const float* __restrict__ g0,
    const float* __restrict__ b0, const float* __restrict__ mm0,
    const float* __restrict__ mv0,
    const float* __restrict__ w1, const float* __restrict__ g1,
    const float* __restrict__ b1_, const float* __restrict__ mm1,
    const float* __restrict__ mv1,
    const float* __restrict__ w2, const float* __restrict__ g2,
    const float* __restrict__ b2_, const float* __restrict__ mm2,
    const float* __restrict__ mv2,
    float* __restrict__ out1)
{
  const int tid = threadIdx.x;
  const int BS0 = blockIdx.x * 2;

  __shared__ __align__(16) float xT[2][67][36];  // input feats (c-major); reused as a2
  __shared__ __align__(16) float a1[2][64][36];  // layer-1 out; reused as k-max partials
  __shared__ __align__(16) float wbuf[8192];     // current layer weights (f32)

  // ---- gather: x = [grouped_xyz - new_xyz (3) ; grouped_points (64)] ----
  {
    const int sg = tid >> 7;
    const int j  = (tid >> 2) & 31;
    const int cq = tid & 3;
    const int S  = BS0 + sg;
    const int bb = S >> 10;
    const int n  = knn[(size_t)S * 32 + j] & (N_PTS - 1);   // defensive clamp
    const float* pbase = points + ((size_t)bb * N_PTS + n) * 64;
    const float* xbase = xyz + ((size_t)bb * N_PTS + n) * 3;
    for (int c = cq; c < 67; c += 4) {
      float v;
      if (c < 3) v = __fsub_rn(xbase[c], newxyz[(size_t)S * 3 + c]);
      else       v = pbase[c - 3];
      xT[sg][c][j] = v;
    }
  }
  for (int i = tid; i < 67 * 64; i += 256) wbuf[i] = w0[i];
  __syncthreads();

  const int sg = tid >> 7;
  const int t  = tid & 127;

  // ---- layer 1: 67 -> 64 ----
  {
    const int ot = t & 15, kt = t >> 4;
    const int o0 = ot * 4, k0 = kt * 4;
    float acc[4][4] = {};
    for (int c = 0; c < 67; ++c) {
      float4 xv = *(const float4*)&xT[sg][c][k0];
      float4 wq = *(const float4*)&wbuf[c * 64 + o0];
      float wv[4] = { wq.x, wq.y, wq.z, wq.w };
      float xs[4] = { xv.x, xv.y, xv.z, xv.w };
#pragma unroll
      for (int a = 0; a < 4; ++a)
#pragma unroll
        for (int k2 = 0; k2 < 4; ++k2)
          acc[a][k2] = fmaf(wv[a], xs[k2], acc[a][k2]);
    }
#pragma unroll
    for (int jj = 0; jj < 4; ++jj) {
      int o = o0 + jj;
      float A  = rsqrtf(mv0[o] + 1e-3f) * g0[o];
      float Bc = b0[o] - mm0[o] * A;
      float4 y;
      y.x = fmaxf(fmaf(acc[jj][0], A, Bc), 0.0f);
      y.y = fmaxf(fmaf(acc[jj][1], A, Bc), 0.0f);
      y.z = fmaxf(fmaf(acc[jj][2], A, Bc), 0.0f);
      y.w = fmaxf(fmaf(acc[jj][3], A, Bc), 0.0f);
      *(float4*)&a1[sg][o][k0] = y;
    }
  }
  __syncthreads();
  for (int i = tid; i < 64 * 64; i += 256) wbuf[i] = w1[i];
  __syncthreads();

  // ---- layer 2: 64 -> 64 (reads a1, writes a2 = xT region) ----
  {
    const int ot = t & 15, kt = t >> 4;
    const int o0 = ot * 4, k0 = kt * 4;
    float acc[4][4] = {};
    for (int c = 0; c < 64; ++c) {
      float4 xv = *(const float4*)&a1[sg][c][k0];
      float4 wq = *(const float4*)&wbuf[c * 64 + o0];
      float wv[4] = { wq.x, wq.y, wq.z, wq.w };
      float xs[4] = { xv.x, xv.y, xv.z, xv.w };
#pragma unroll
      for (int a = 0; a < 4; ++a)
#pragma unroll
        for (int k2 = 0; k2 < 4; ++k2)
          acc[a][k2] = fmaf(wv[a], xs[k2], acc[a][k2]);
    }
#pragma unroll
    for (int jj = 0; jj < 4; ++jj) {
      int o = o0 + jj;
      float A  = rsqrtf(mv1[o] + 1e-3f) * g1[o];
      float Bc = b1_[o] - mm1[o] * A;
      float4 y;
      y.x = fmaxf(fmaf(acc[jj][0], A, Bc), 0.0f);
      y.y = fmaxf(fmaf(acc[jj][1], A, Bc), 0.0f);
      y.z = fmaxf(fmaf(acc[jj][2], A, Bc), 0.0f);
      y.w = fmaxf(fmaf(acc[jj][3], A, Bc), 0.0f);
      *(float4*)&xT[sg][o][k0] = y;
    }
  }
  __syncthreads();
  for (int i = tid; i < 64 * 128; i += 256) wbuf[i] = w2[i];
  __syncthreads();

  // ---- layer 3: 64 -> 128, BN+ReLU folded into max over k ----
  float* pm = &a1[0][0][0];          // [2][128][4] partial maxima
  {
    const int ot = t & 31, kt = t >> 5;
    const int o0 = ot * 4, k0 = kt * 8;
    float acc[4][8] = {};
    for (int c = 0; c < 64; ++c) {
      float4 xa = *(const float4*)&xT[sg][c][k0];
      float4 xb = *(const float4*)&xT[sg][c][k0 + 4];
      float4 wq = *(const float4*)&wbuf[c * 128 + o0];
      float wv[4] = { wq.x, wq.y, wq.z, wq.w };
      float xs[8] = { xa.x, xa.y, xa.z, xa.w, xb.x, xb.y, xb.z, xb.w };
#pragma unroll
      for (int a = 0; a < 4; ++a)
#pragma unroll
        for (int k2 = 0; k2 < 8; ++k2)
          acc[a][k2] = fmaf(wv[a], xs[k2], acc[a][k2]);
    }
#pragma unroll
    for (int jj = 0; jj < 4; ++jj) {
      int o = o0 + jj;
      float A  = rsqrtf(mv2[o] + 1e-3f) * g2[o];
      float Bc = b2_[o] - mm2[o] * A;
      float m = 0.0f;                 // relu>=0: max(0, max_k bn) == max_k relu(bn)
#pragma unroll
      for (int kk = 0; kk < 8; ++kk)
        m = fmaxf(m, fmaf(acc[jj][kk], A, Bc));
      pm[((sg * 128 + o) << 2) + kt] = m;
    }
  }
  __syncthreads();
  {
    const int sg2 = tid >> 7, o = tid & 127;
    const int basep = (sg2 * 128 + o) << 2;
    float m = fmaxf(fmaxf(pm[basep + 0], pm[basep + 1]),
                    fmaxf(pm[basep + 2], pm[basep + 3]));
    out1[(size_t)(BS0 + sg2) * 128 + o] = m;
  }
}

extern "C" void kernel_launch(void* const* d_in, const int* in_sizes, int n_in,
                              void* d_out, int out_size, void* d_ws, size_t ws_size,
                              hipStream_t stream) {
  const float* xyz    = (const float*)d_in[0];
  const float* points = (const float*)d_in[1];
  const float* w0  = (const float*)d_in[2];
  const float* g0  = (const float*)d_in[3];
  const float* b0  = (const float*)d_in[4];
  const float* mm0 = (const float*)d_in[5];
  const float* mv0 = (const float*)d_in[6];
  const float* w1  = (const float*)d_in[7];
  const float* g1  = (const float*)d_in[8];
  const float* b1  = (const float*)d_in[9];
  const float* mm1 = (const float*)d_in[10];
  const float* mv1 = (const float*)d_in[11];
  const float* w2  = (const float*)d_in[12];
  const float* g2  = (const float*)d_in[13];
  const float* b2  = (const float*)d_in[14];
  const float* mm2 = (const float*)d_in[15];
  const float* mv2 = (const float*)d_in[16];

  float* out      = (float*)d_out;                       // new_xyz f32[12288]
  float* out_pts  = out + (size_t)4 * 1024 * 3;          // new_points f32[524288]
  int*   knn      = (int*)d_ws;                          // 4*1024*32 int32

  fps_kernel<<<4, 512, 0, stream>>>(xyz, out);
  knn_kernel<<<4096, 256, 0, stream>>>(xyz, out, knn);
  mlp_kernel<<<2048, 256, 0, stream>>>(xyz, points, out, knn,
      w0, g0, b0, mm0, mv0, w1, g1, b1, mm1, mv1, w2, g2, b2, mm2, mv2,
      out_pts);
}